// Round 1
// baseline (433.153 us; speedup 1.0000x reference)
//
#include <hip/hip_runtime.h>
#include <hip/hip_bf16.h>

// GAT layer: out = elu( softmax(mask(leakyrelu(s1[i]+s2[j]))) @ (h@W) )
// N=8192, F_IN=512, F_OUT=64. HBM floor = adj stream (256 MiB) ~= 43 us.
//
// ws layout:
//   WT   f16 [64][512]   @ 0        (65536 B)   W transposed, f16
//   WhT  f16 [64][8192]  @ 65536    (1048576 B) Wh transposed, f16 (MFMA B operand)
//   s1   f32 [8192]      @ 1114112
//   s2   f32 [8192]      @ 1146880
//   mx   f32 [1]         @ 1179648  (global max of s2)

typedef _Float16 f16;
typedef _Float16 f16x8 __attribute__((ext_vector_type(8)));
typedef float f32x4 __attribute__((ext_vector_type(4)));

#define GAT_N 8192
#define GAT_FIN 512
#define GAT_FOUT 64
#define GAT_ALPHA 0.2f

// ---------------- K0: W [512][64] f32 -> WT [64][512] f16 ----------------
__global__ void k0_wtrans(const float* __restrict__ W, f16* __restrict__ WT) {
    int idx = blockIdx.x * blockDim.x + threadIdx.x;   // 0..32767
    int k = idx >> 6, c = idx & 63;
    WT[c * GAT_FIN + k] = (f16)W[idx];
}

// ---------------- K1: Wh = h@W (f16 MFMA), fused s1/s2, emit WhT f16 -----
// 512 blocks x 1 wave; wave computes 16 rows x 64 cols via 4 acc tiles.
// A layout: A[m=lane&15][k=quad*8+j]; B layout: B[k=quad*8+j][n=lane&15];
// C/D: col=lane&15, row=quad*4+reg (verified gfx950 mappings).
__global__ __launch_bounds__(64) void k1_gemm(const float* __restrict__ h,
        const f16* __restrict__ WT, const float* __restrict__ a,
        f16* __restrict__ WhT, float* __restrict__ s1, float* __restrict__ s2) {
    int lane = threadIdx.x & 63;
    int l15 = lane & 15, quad = lane >> 4;
    int rb = blockIdx.x * 16;
    size_t arow = (size_t)(rb + l15) * GAT_FIN;   // A-operand row for this lane

    f32x4 acc[4] = {};
    for (int k0 = 0; k0 < GAT_FIN; k0 += 32) {
        int kb = k0 + quad * 8;
        const float4* hp = (const float4*)(h + arow + kb);
        float4 h0 = hp[0], h1 = hp[1];
        f16x8 af = { (f16)h0.x, (f16)h0.y, (f16)h0.z, (f16)h0.w,
                     (f16)h1.x, (f16)h1.y, (f16)h1.z, (f16)h1.w };
#pragma unroll
        for (int t = 0; t < 4; t++) {
            f16x8 bf = *(const f16x8*)(WT + (t * 16 + l15) * GAT_FIN + kb);
            acc[t] = __builtin_amdgcn_mfma_f32_16x16x32_f16(af, bf, acc[t], 0, 0, 0);
        }
    }

    // Epilogue: acc[t][reg] = Wh[rb + quad*4+reg][t*16+l15] (fp32, good precision)
    float a1v[4], a2v[4];
#pragma unroll
    for (int t = 0; t < 4; t++) {
        a1v[t] = a[t * 16 + l15];
        a2v[t] = a[GAT_FOUT + t * 16 + l15];
    }
#pragma unroll
    for (int reg = 0; reg < 4; reg++) {
        int r = rb + quad * 4 + reg;
        float p1 = 0.f, p2 = 0.f;
#pragma unroll
        for (int t = 0; t < 4; t++) {
            float v = acc[t][reg];
            WhT[(size_t)(t * 16 + l15) * GAT_N + r] = (f16)v;  // scattered 2B; K1 is tiny
            p1 += v * a1v[t];
            p2 += v * a2v[t];
        }
        // reduce over the 16 l15 lanes (cols) within each quad
#pragma unroll
        for (int off = 1; off < 16; off <<= 1) {
            p1 += __shfl_xor(p1, off);
            p2 += __shfl_xor(p2, off);
        }
        if (l15 == 0) { s1[r] = p1; s2[r] = p2; }
    }
}

// ---------------- K2: mx = max(s2) -------------------------------------
__global__ void k2_max(const float* __restrict__ s2, float* __restrict__ mx) {
    __shared__ float red[256];
    float m = -1e30f;
    for (int i = threadIdx.x; i < GAT_N; i += 256) m = fmaxf(m, s2[i]);
    red[threadIdx.x] = m;
    __syncthreads();
    for (int s = 128; s > 0; s >>= 1) {
        if (threadIdx.x < s) red[threadIdx.x] = fmaxf(red[threadIdx.x], red[threadIdx.x + s]);
        __syncthreads();
    }
    if (threadIdx.x == 0) mx[0] = red[0];
}

// ---------------- K3: fused mask+softmax+(P@Wh)+elu ---------------------
// 512 blocks (16 rows each) x 8 waves (j-dim split 8-way -> 16 waves/CU).
// Unnormalized p = exp(leakyrelu(s1+s2) - C_row) with C_row = leakyrelu(s1+max_s2)
// (upper bound -> exponents <= 0; constant cancels in num/den). Masked -> p=0.
__global__ __launch_bounds__(512) void k3_attn(const int* __restrict__ adj,
        const f16* __restrict__ WhT, const float* __restrict__ s1,
        const float* __restrict__ s2, const float* __restrict__ mxp,
        float* __restrict__ out) {
    __shared__ float accbuf[8][16][64];   // 32 KB cross-wave combine
    __shared__ float dbuf[8][16];

    int tid = threadIdx.x;
    int w = tid >> 6, lane = tid & 63;
    int l15 = lane & 15, quad = lane >> 4;
    int rb = blockIdx.x * 16;
    int row = rb + l15;                    // A-operand (P) row for this lane

    float s1r = s1[row];
    float cr = s1r + mxp[0];
    cr = fmaxf(cr, GAT_ALPHA * cr);        // leakyrelu (alpha in (0,1))

    f32x4 acc[4] = {};
    float dacc = 0.f;
    const int* adjrow = adj + (size_t)row * GAT_N;

    for (int step = w; step < GAT_N / 32; step += 8) {
        int kb = step * 32 + quad * 8;
        int4 av0 = *(const int4*)(adjrow + kb);
        int4 av1 = *(const int4*)(adjrow + kb + 4);
        float4 sv0 = *(const float4*)(s2 + kb);
        float4 sv1 = *(const float4*)(s2 + kb + 4);

        int   am[8] = { av0.x, av0.y, av0.z, av0.w, av1.x, av1.y, av1.z, av1.w };
        float sv[8] = { sv0.x, sv0.y, sv0.z, sv0.w, sv1.x, sv1.y, sv1.z, sv1.w };

        f16x8 af;
#pragma unroll
        for (int j = 0; j < 8; j++) {
            float e = s1r + sv[j];
            e = fmaxf(e, GAT_ALPHA * e);               // leakyrelu
            float pf = __expf(e - cr);                 // exponent <= 0, no overflow
            pf = (am[j] > 0) ? pf : 0.0f;              // mask
            dacc += pf;
            af[j] = (f16)pf;
        }
#pragma unroll
        for (int t = 0; t < 4; t++) {
            f16x8 bf = *(const f16x8*)(WhT + (size_t)(t * 16 + l15) * GAT_N + kb);
            acc[t] = __builtin_amdgcn_mfma_f32_16x16x32_f16(af, bf, acc[t], 0, 0, 0);
        }
    }

    // denominator: sum the 4 quads (same row, different k-subsets)
    dacc += __shfl_xor(dacc, 16);
    dacc += __shfl_xor(dacc, 32);

    // C/D layout: acc[t][reg] = tile[row=quad*4+reg][col=t*16+l15]
#pragma unroll
    for (int t = 0; t < 4; t++)
#pragma unroll
        for (int reg = 0; reg < 4; reg++)
            accbuf[w][quad * 4 + reg][t * 16 + l15] = acc[t][reg];
    if (quad == 0) dbuf[w][l15] = dacc;
    __syncthreads();

    // combine 8 waves, normalize, elu, store (coalesced fp32)
    for (int o = tid; o < 16 * 64; o += 512) {
        int r = o >> 6, c = o & 63;
        float num = 0.f, den = 0.f;
#pragma unroll
        for (int ww = 0; ww < 8; ww++) { num += accbuf[ww][r][c]; den += dbuf[ww][r]; }
        float hp = num / den;
        out[(size_t)(rb + r) * GAT_FOUT + c] = hp > 0.f ? hp : expm1f(hp);
    }
}

// ---------------- launch -------------------------------------------------
extern "C" void kernel_launch(void* const* d_in, const int* in_sizes, int n_in,
                              void* d_out, int out_size, void* d_ws, size_t ws_size,
                              hipStream_t stream) {
    const float* h   = (const float*)d_in[0];
    const float* W   = (const float*)d_in[1];
    const float* a   = (const float*)d_in[2];
    const int*   adj = (const int*)d_in[3];
    float* out = (float*)d_out;

    char* ws = (char*)d_ws;
    f16*   WT  = (f16*)ws;
    f16*   WhT = (f16*)(ws + 65536);
    float* s1  = (float*)(ws + 65536 + 1048576);
    float* s2  = (float*)(ws + 65536 + 1048576 + 32768);
    float* mx  = (float*)(ws + 65536 + 1048576 + 65536);

    k0_wtrans<<<128, 256, 0, stream>>>(W, WT);
    k1_gemm<<<512, 64, 0, stream>>>(h, WT, a, WhT, s1, s2);
    k2_max<<<1, 256, 0, stream>>>(s2, mx);
    k3_attn<<<512, 512, 0, stream>>>(adj, WhT, s1, s2, mx, out);
}

// Round 2
// 409.798 us; speedup vs baseline: 1.0570x; 1.0570x over previous
//
#include <hip/hip_runtime.h>
#include <hip/hip_bf16.h>

// GAT layer: out = elu( softmax(mask(leakyrelu(s1[i]+s2[j]))) @ (h@W) )
// N=8192, F_IN=512, F_OUT=64. HBM floor = adj stream (256 MiB) ~= 40 us.
//
// Round 2: k3 restructured — contiguous adj reads (one row per half-wave,
// 512-B segments), p computed at load, staged into LDS in MFMA A-frag
// layout (frag-major, canonical b128 reads), double-buffered + software
// pipelined. accbuf aliases pbuf (union) to stay under the 64-KB block cap.
//
// ws layout:
//   WT   f16 [64][512]   @ 0        W transposed, f16
//   WhT  f16 [64][8192]  @ 65536    Wh transposed, f16 (MFMA B operand)
//   s1   f32 [8192]      @ 1114112
//   s2   f32 [8192]      @ 1146880
//   mx   f32 [1]         @ 1179648  (global max of s2)

typedef _Float16 f16;
typedef _Float16 f16x2 __attribute__((ext_vector_type(2)));
typedef _Float16 f16x8 __attribute__((ext_vector_type(8)));
typedef float f32x4 __attribute__((ext_vector_type(4)));

#define GAT_N 8192
#define GAT_FIN 512
#define GAT_FOUT 64
#define GAT_ALPHA 0.2f

// ---------------- K0: W [512][64] f32 -> WT [64][512] f16 ----------------
__global__ void k0_wtrans(const float* __restrict__ W, f16* __restrict__ WT) {
    int idx = blockIdx.x * blockDim.x + threadIdx.x;   // 0..32767
    int k = idx >> 6, c = idx & 63;
    WT[c * GAT_FIN + k] = (f16)W[idx];
}

// ---------------- K1: Wh = h@W (f16 MFMA), fused s1/s2, emit WhT f16 -----
__global__ __launch_bounds__(64) void k1_gemm(const float* __restrict__ h,
        const f16* __restrict__ WT, const float* __restrict__ a,
        f16* __restrict__ WhT, float* __restrict__ s1, float* __restrict__ s2) {
    int lane = threadIdx.x & 63;
    int l15 = lane & 15, quad = lane >> 4;
    int rb = blockIdx.x * 16;
    size_t arow = (size_t)(rb + l15) * GAT_FIN;

    f32x4 acc[4] = {};
    for (int k0 = 0; k0 < GAT_FIN; k0 += 32) {
        int kb = k0 + quad * 8;
        const float4* hp = (const float4*)(h + arow + kb);
        float4 h0 = hp[0], h1 = hp[1];
        f16x8 af = { (f16)h0.x, (f16)h0.y, (f16)h0.z, (f16)h0.w,
                     (f16)h1.x, (f16)h1.y, (f16)h1.z, (f16)h1.w };
#pragma unroll
        for (int t = 0; t < 4; t++) {
            f16x8 bf = *(const f16x8*)(WT + (t * 16 + l15) * GAT_FIN + kb);
            acc[t] = __builtin_amdgcn_mfma_f32_16x16x32_f16(af, bf, acc[t], 0, 0, 0);
        }
    }

    float a1v[4], a2v[4];
#pragma unroll
    for (int t = 0; t < 4; t++) {
        a1v[t] = a[t * 16 + l15];
        a2v[t] = a[GAT_FOUT + t * 16 + l15];
    }
#pragma unroll
    for (int reg = 0; reg < 4; reg++) {
        int r = rb + quad * 4 + reg;
        float p1 = 0.f, p2 = 0.f;
#pragma unroll
        for (int t = 0; t < 4; t++) {
            float v = acc[t][reg];
            WhT[(size_t)(t * 16 + l15) * GAT_N + r] = (f16)v;
            p1 += v * a1v[t];
            p2 += v * a2v[t];
        }
#pragma unroll
        for (int off = 1; off < 16; off <<= 1) {
            p1 += __shfl_xor(p1, off);
            p2 += __shfl_xor(p2, off);
        }
        if (l15 == 0) { s1[r] = p1; s2[r] = p2; }
    }
}

// ---------------- K2: mx = max(s2) -------------------------------------
__global__ void k2_max(const float* __restrict__ s2, float* __restrict__ mx) {
    __shared__ float red[256];
    float m = -1e30f;
    for (int i = threadIdx.x; i < GAT_N; i += 256) m = fmaxf(m, s2[i]);
    red[threadIdx.x] = m;
    __syncthreads();
    for (int s = 128; s > 0; s >>= 1) {
        if (threadIdx.x < s) red[threadIdx.x] = fmaxf(red[threadIdx.x], red[threadIdx.x + s]);
        __syncthreads();
    }
    if (threadIdx.x == 0) mx[0] = red[0];
}

// ---------------- K3: fused mask+softmax+(P@Wh)+elu ---------------------
// 512 blocks (16 rows) x 8 waves. Per round (512 cols): each half-wave
// streams ONE adj row contiguously (int4/lane, 512-B segments), computes
// p = exp(leakyrelu(s1+s2) - C_row) * mask, writes f16 p into LDS in the
// MFMA A-frag layout [step][lane=quad*16+m][8]. MFMA phase: canonical
// ds_read_b128 A-frags + L2-resident WhT B-frags. Double-buffered LDS,
// next-round loads issued before MFMA to hide HBM latency.
__global__ __launch_bounds__(512, 4) void k3_attn(const int* __restrict__ adj,
        const f16* __restrict__ WhT, const float* __restrict__ s1,
        const float* __restrict__ s2, const float* __restrict__ mxp,
        float* __restrict__ out) {
    // pbuf: 2 buffers x 16 steps x 520 f16 (512 data + 8 pad for b128 align)
    // accbuf (8*16*64 f32 = 32 KB) aliases pbuf (33,280 B) — used only after
    // the last MFMA round (separated by __syncthreads).
    __shared__ __align__(16) char smem[2 * 16 * 520 * 2];
    f16* pbuf = (f16*)smem;
    float (*accbuf)[16][64] = (float (*)[16][64])smem;
    __shared__ float dbuf2[16];

    int tid = threadIdx.x;
    int w = tid >> 6, lane = tid & 63;
    int l15 = lane & 15, quad = lane >> 4;
    int hhalf = lane >> 5, q = lane & 31;
    int rb = blockIdx.x * 16;
    int r = 2 * w + hhalf;                 // staged row (0..15), one per half-wave

    float s1r = s1[rb + r];
    float cr = s1r + mxp[0];
    cr = fmaxf(cr, GAT_ALPHA * cr);        // leakyrelu of row upper bound
    const int* adjrow = adj + (size_t)(rb + r) * GAT_N;

    float dacc = 0.f;
    f32x4 acc[4] = {};
    int4   av[4];
    float4 sv[4];

    // element (row r, col c) -> frag slot: step=c>>5, lane'=((c>>3)&3)*16+r, j=c&7
    auto stage = [&](int bb) {
#pragma unroll
        for (int p = 0; p < 4; p++) {
            int   am[4]  = { av[p].x, av[p].y, av[p].z, av[p].w };
            float svv[4] = { sv[p].x, sv[p].y, sv[p].z, sv[p].w };
            // c0 = p*128 + q*4 within the round
            int base = (4 * p + (q >> 3)) * 520 + ((q >> 1) & 3) * 128 + r * 8 + (q & 1) * 4;
            f16 pf[4];
#pragma unroll
            for (int j = 0; j < 4; j++) {
                float e = s1r + svv[j];
                e = fmaxf(e, GAT_ALPHA * e);            // leakyrelu
                float pv = __expf(e - cr);              // exponent <= ~0
                pv = (am[j] > 0) ? pv : 0.0f;           // mask
                dacc += pv;
                pf[j] = (f16)pv;
            }
            f16x2 lo = { pf[0], pf[1] }, hi = { pf[2], pf[3] };
            *(f16x2*)&pbuf[bb * 8320 + base]     = lo;
            *(f16x2*)&pbuf[bb * 8320 + base + 2] = hi;
        }
    };

    // prologue: load + stage round 0 into buf 0
#pragma unroll
    for (int p = 0; p < 4; p++) {
        int c0 = p * 128 + q * 4;
        av[p] = *(const int4*)(adjrow + c0);
        sv[p] = *(const float4*)(s2 + c0);
    }
    stage(0);
    __syncthreads();

    for (int rd = 0; rd < 16; rd++) {
        int b = rd & 1;
        if (rd < 15) {
            // issue next round's loads first — MFMA below hides their latency
#pragma unroll
            for (int p = 0; p < 4; p++) {
                int c0 = (rd + 1) * 512 + p * 128 + q * 4;
                av[p] = *(const int4*)(adjrow + c0);
                sv[p] = *(const float4*)(s2 + c0);
            }
        }
        // MFMA phase: this wave owns steps 2w, 2w+1 of the current round
#pragma unroll
        for (int sl = 0; sl < 2; sl++) {
            int s_loc = 2 * w + sl;
            f16x8 af = *(const f16x8*)&pbuf[b * 8320 + s_loc * 520 + lane * 8];
            int kb = rd * 512 + s_loc * 32 + quad * 8;
#pragma unroll
            for (int t = 0; t < 4; t++) {
                f16x8 bf = *(const f16x8*)(WhT + (size_t)(t * 16 + l15) * GAT_N + kb);
                acc[t] = __builtin_amdgcn_mfma_f32_16x16x32_f16(af, bf, acc[t], 0, 0, 0);
            }
        }
        if (rd < 15) stage(1 - b);
        __syncthreads();
    }

    // epilogue: accbuf aliases pbuf — safe, all MFMA reads are behind the barrier
#pragma unroll
    for (int t = 0; t < 4; t++)
#pragma unroll
        for (int reg = 0; reg < 4; reg++)
            accbuf[w][quad * 4 + reg][t * 16 + l15] = acc[t][reg];
    // denominator: reduce over the 32 lanes of this half-wave (full row)
#pragma unroll
    for (int off = 16; off >= 1; off >>= 1) dacc += __shfl_xor(dacc, off);
    if (q == 0) dbuf2[r] = dacc;
    __syncthreads();

    for (int o = tid; o < 16 * 64; o += 512) {
        int rr = o >> 6, c = o & 63;
        float num = 0.f;
#pragma unroll
        for (int ww = 0; ww < 8; ww++) num += accbuf[ww][rr][c];
        float hp = num / dbuf2[rr];
        out[(size_t)(rb + rr) * GAT_FOUT + c] = hp > 0.f ? hp : expm1f(hp);
    }
}

// ---------------- launch -------------------------------------------------
extern "C" void kernel_launch(void* const* d_in, const int* in_sizes, int n_in,
                              void* d_out, int out_size, void* d_ws, size_t ws_size,
                              hipStream_t stream) {
    const float* h   = (const float*)d_in[0];
    const float* W   = (const float*)d_in[1];
    const float* a   = (const float*)d_in[2];
    const int*   adj = (const int*)d_in[3];
    float* out = (float*)d_out;

    char* ws = (char*)d_ws;
    f16*   WT  = (f16*)ws;
    f16*   WhT = (f16*)(ws + 65536);
    float* s1  = (float*)(ws + 65536 + 1048576);
    float* s2  = (float*)(ws + 65536 + 1048576 + 32768);
    float* mx  = (float*)(ws + 65536 + 1048576 + 65536);

    k0_wtrans<<<128, 256, 0, stream>>>(W, WT);
    k1_gemm<<<512, 64, 0, stream>>>(h, WT, a, WhT, s1, s2);
    k2_max<<<1, 256, 0, stream>>>(s2, mx);
    k3_attn<<<512, 512, 0, stream>>>(adj, WhT, s1, s2, mx, out);
}

// Round 3
// 407.809 us; speedup vs baseline: 1.0621x; 1.0049x over previous
//
#include <hip/hip_runtime.h>
#include <hip/hip_bf16.h>

// GAT layer: out = elu( softmax(mask(leakyrelu(s1[i]+s2[j]))) @ (h@W) )
// N=8192, F_IN=512, F_OUT=64. HBM floor = adj stream (256 MiB) ~= 40 us.
//
// Round 3: (1) k1 K-split 4 waves/block (2048 waves, was 512) + f16x4 WhT
// stores; (2) k2 (max s2) folded into k3 pre-phase — one less launch;
// (3) nontemporal adj loads (stream-once, keep L2 for WhT/s2).
//
// ws layout:
//   WT   f16 [64][512]   @ 0        W transposed, f16
//   WhT  f16 [64][8192]  @ 65536    Wh transposed, f16 (MFMA B operand)
//   s1   f32 [8192]      @ 1114112
//   s2   f32 [8192]      @ 1146880

typedef _Float16 f16;
typedef _Float16 f16x2 __attribute__((ext_vector_type(2)));
typedef _Float16 f16x4 __attribute__((ext_vector_type(4)));
typedef _Float16 f16x8 __attribute__((ext_vector_type(8)));
typedef float f32x4 __attribute__((ext_vector_type(4)));
typedef int   i32x4 __attribute__((ext_vector_type(4)));

#define GAT_N 8192
#define GAT_FIN 512
#define GAT_FOUT 64
#define GAT_ALPHA 0.2f

// ---------------- K0: W [512][64] f32 -> WT [64][512] f16 ----------------
__global__ void k0_wtrans(const float* __restrict__ W, f16* __restrict__ WT) {
    int idx = blockIdx.x * blockDim.x + threadIdx.x;   // 0..32767
    int k = idx >> 6, c = idx & 63;
    WT[c * GAT_FIN + k] = (f16)W[idx];
}

// ---------------- K1: Wh = h@W (f16 MFMA), fused s1/s2, emit WhT f16 -----
// 512 blocks x 4 waves. Wave w covers k in [w*128, (w+1)*128); partial
// accumulators combined via LDS; epilogue: wave w owns col-tile t=w.
__global__ __launch_bounds__(256) void k1_gemm(const float* __restrict__ h,
        const f16* __restrict__ WT, const float* __restrict__ a,
        f16* __restrict__ WhT, float* __restrict__ s1, float* __restrict__ s2) {
    __shared__ float pacc[4][4][64][4];     // [wave][t][lane][reg] 16 KB
    __shared__ float s1red[4][16], s2red[4][16];

    int tid = threadIdx.x;
    int w = tid >> 6, lane = tid & 63;
    int l15 = lane & 15, quad = lane >> 4;
    int rb = blockIdx.x * 16;
    size_t arow = (size_t)(rb + l15) * GAT_FIN;

    f32x4 acc[4] = {};
#pragma unroll
    for (int ks = 0; ks < 4; ks++) {
        int kb = w * 128 + ks * 32 + quad * 8;
        const float4* hp = (const float4*)(h + arow + kb);
        float4 h0 = hp[0], h1 = hp[1];
        f16x8 af = { (f16)h0.x, (f16)h0.y, (f16)h0.z, (f16)h0.w,
                     (f16)h1.x, (f16)h1.y, (f16)h1.z, (f16)h1.w };
#pragma unroll
        for (int t = 0; t < 4; t++) {
            f16x8 bf = *(const f16x8*)(WT + (t * 16 + l15) * GAT_FIN + kb);
            acc[t] = __builtin_amdgcn_mfma_f32_16x16x32_f16(af, bf, acc[t], 0, 0, 0);
        }
    }
#pragma unroll
    for (int t = 0; t < 4; t++)
        *(f32x4*)&pacc[w][t][lane][0] = acc[t];
    __syncthreads();

    // wave w finalizes col-tile t=w: C[row=quad*4+reg][col=w*16+l15]
    float a1v = a[w * 16 + l15];
    float a2v = a[GAT_FOUT + w * 16 + l15];
    float vreg[4];
#pragma unroll
    for (int reg = 0; reg < 4; reg++) {
        float v = 0.f;
#pragma unroll
        for (int ww = 0; ww < 4; ww++) v += pacc[ww][w][lane][reg];
        vreg[reg] = v;
    }
    f16x4 pk = { (f16)vreg[0], (f16)vreg[1], (f16)vreg[2], (f16)vreg[3] };
    *(f16x4*)(WhT + (size_t)(w * 16 + l15) * GAT_N + rb + quad * 4) = pk;  // 8-B store

#pragma unroll
    for (int reg = 0; reg < 4; reg++) {
        float c1 = vreg[reg] * a1v, c2 = vreg[reg] * a2v;
#pragma unroll
        for (int off = 1; off < 16; off <<= 1) {   // reduce over 16 cols (l15)
            c1 += __shfl_xor(c1, off);
            c2 += __shfl_xor(c2, off);
        }
        if (l15 == 0) { s1red[w][quad * 4 + reg] = c1; s2red[w][quad * 4 + reg] = c2; }
    }
    __syncthreads();
    if (tid < 16) {
        float t1 = 0.f, t2 = 0.f;
#pragma unroll
        for (int ww = 0; ww < 4; ww++) { t1 += s1red[ww][tid]; t2 += s2red[ww][tid]; }
        s1[rb + tid] = t1;
        s2[rb + tid] = t2;
    }
}

// ---------------- K3: fused max+mask+softmax+(P@Wh)+elu ------------------
// 512 blocks (16 rows) x 8 waves. Pre-phase: block-local max(s2) (32 KB,
// L2-hot; per-row constants cancel in num/den so cross-block agreement is
// not required). Main loop: each half-wave streams ONE adj row contiguously
// (nontemporal int4), p computed at load, staged f16 into LDS in MFMA
// A-frag layout, double-buffered; MFMA against L2-resident WhT.
__global__ __launch_bounds__(512, 4) void k3_attn(const int* __restrict__ adj,
        const f16* __restrict__ WhT, const float* __restrict__ s1,
        const float* __restrict__ s2, float* __restrict__ out) {
    // pbuf: 2 x 16 steps x 520 f16; accbuf (32 KB) aliases pbuf (33,280 B)
    __shared__ __align__(16) char smem[2 * 16 * 520 * 2];
    f16* pbuf = (f16*)smem;
    float (*accbuf)[16][64] = (float (*)[16][64])smem;
    __shared__ float dbuf2[16];
    __shared__ float mred[8];

    int tid = threadIdx.x;
    int w = tid >> 6, lane = tid & 63;
    int l15 = lane & 15, quad = lane >> 4;
    int hhalf = lane >> 5, q = lane & 31;
    int rb = blockIdx.x * 16;
    int r = 2 * w + hhalf;                 // staged row (0..15), one per half-wave

    // ---- pre-phase: mxv = max(s2) (block-local) ----
    float m = -1e30f;
    for (int i = tid; i < GAT_N; i += 512) m = fmaxf(m, s2[i]);
#pragma unroll
    for (int off = 32; off >= 1; off >>= 1) m = fmaxf(m, __shfl_xor(m, off));
    if (lane == 0) mred[w] = m;
    __syncthreads();
    float mxv = mred[0];
#pragma unroll
    for (int ww = 1; ww < 8; ww++) mxv = fmaxf(mxv, mred[ww]);

    float s1r = s1[rb + r];
    float cr = s1r + mxv;
    cr = fmaxf(cr, GAT_ALPHA * cr);        // leakyrelu of row upper bound
    const int* adjrow = adj + (size_t)(rb + r) * GAT_N;

    float dacc = 0.f;
    f32x4 acc[4] = {};
    i32x4  av[4];
    float4 sv[4];

    // element (row r, col c) -> frag slot: step=c>>5, lane'=((c>>3)&3)*16+r, j=c&7
    auto stage = [&](int bb) {
#pragma unroll
        for (int p = 0; p < 4; p++) {
            float svv[4] = { sv[p].x, sv[p].y, sv[p].z, sv[p].w };
            int base = (4 * p + (q >> 3)) * 520 + ((q >> 1) & 3) * 128 + r * 8 + (q & 1) * 4;
            f16 pf[4];
#pragma unroll
            for (int j = 0; j < 4; j++) {
                float e = s1r + svv[j];
                e = fmaxf(e, GAT_ALPHA * e);            // leakyrelu
                float pv = __expf(e - cr);              // exponent <= ~0
                pv = (av[p][j] > 0) ? pv : 0.0f;        // mask
                dacc += pv;
                pf[j] = (f16)pv;
            }
            f16x2 lo = { pf[0], pf[1] }, hi = { pf[2], pf[3] };
            *(f16x2*)&pbuf[bb * 8320 + base]     = lo;
            *(f16x2*)&pbuf[bb * 8320 + base + 2] = hi;
        }
    };

    // prologue: load + stage round 0 into buf 0
#pragma unroll
    for (int p = 0; p < 4; p++) {
        int c0 = p * 128 + q * 4;
        av[p] = __builtin_nontemporal_load((const i32x4*)(adjrow + c0));
        sv[p] = *(const float4*)(s2 + c0);
    }
    stage(0);
    __syncthreads();

    for (int rd = 0; rd < 16; rd++) {
        int b = rd & 1;
        if (rd < 15) {
#pragma unroll
            for (int p = 0; p < 4; p++) {
                int c0 = (rd + 1) * 512 + p * 128 + q * 4;
                av[p] = __builtin_nontemporal_load((const i32x4*)(adjrow + c0));
                sv[p] = *(const float4*)(s2 + c0);
            }
        }
#pragma unroll
        for (int sl = 0; sl < 2; sl++) {
            int s_loc = 2 * w + sl;
            f16x8 af = *(const f16x8*)&pbuf[b * 8320 + s_loc * 520 + lane * 8];
            int kb = rd * 512 + s_loc * 32 + quad * 8;
#pragma unroll
            for (int t = 0; t < 4; t++) {
                f16x8 bf = *(const f16x8*)(WhT + (size_t)(t * 16 + l15) * GAT_N + kb);
                acc[t] = __builtin_amdgcn_mfma_f32_16x16x32_f16(af, bf, acc[t], 0, 0, 0);
            }
        }
        if (rd < 15) stage(1 - b);
        __syncthreads();
    }

    // epilogue: accbuf aliases pbuf — safe, all MFMA reads behind the barrier
#pragma unroll
    for (int t = 0; t < 4; t++)
#pragma unroll
        for (int reg = 0; reg < 4; reg++)
            accbuf[w][quad * 4 + reg][t * 16 + l15] = acc[t][reg];
#pragma unroll
    for (int off = 16; off >= 1; off >>= 1) dacc += __shfl_xor(dacc, off);
    if (q == 0) dbuf2[r] = dacc;
    __syncthreads();

    for (int o = tid; o < 16 * 64; o += 512) {
        int rr = o >> 6, c = o & 63;
        float num = 0.f;
#pragma unroll
        for (int ww = 0; ww < 8; ww++) num += accbuf[ww][rr][c];
        float hp = num / dbuf2[rr];
        out[(size_t)(rb + rr) * GAT_FOUT + c] = hp > 0.f ? hp : expm1f(hp);
    }
}

// ---------------- launch -------------------------------------------------
extern "C" void kernel_launch(void* const* d_in, const int* in_sizes, int n_in,
                              void* d_out, int out_size, void* d_ws, size_t ws_size,
                              hipStream_t stream) {
    const float* h   = (const float*)d_in[0];
    const float* W   = (const float*)d_in[1];
    const float* a   = (const float*)d_in[2];
    const int*   adj = (const int*)d_in[3];
    float* out = (float*)d_out;

    char* ws = (char*)d_ws;
    f16*   WT  = (f16*)ws;
    f16*   WhT = (f16*)(ws + 65536);
    float* s1  = (float*)(ws + 65536 + 1048576);
    float* s2  = (float*)(ws + 65536 + 1048576 + 32768);

    k0_wtrans<<<128, 256, 0, stream>>>(W, WT);
    k1_gemm<<<512, 256, 0, stream>>>(h, WT, a, WhT, s1, s2);
    k3_attn<<<512, 512, 0, stream>>>(adj, WhT, s1, s2, out);
}